// Round 14
// baseline (52.240 us; speedup 1.0000x reference)
//
#include <hip/hip_runtime.h>

// SSIM via MFMA, R14: barrier-free wave-self-sufficient staging.
// R13 post-mortem: wall == per-block {DMA issue -> __syncthreads drain of all
// 148 block DMA loads -> compute} convoy (~3500 cyc/block-slot). Fix: wave wv
// only reads patch rows [16wv,16wv+32), so each wave DMAs ITS OWN rows
// (neighbor-wave overlap rows duplicated -- benign same-data LDS races, L2
// hits) and waits on its own vmcnt(0). No __syncthreads before compute in
// interior blocks; one wave's drain overlaps other waves' compute.
// 3 rows per global_load_lds (63 lanes; 84*(l/21)+4*(l%21)==4*l keeps the
// linear lane->dest mapping exact). Edge blocks: per-wave zero-fill +
// barrier BEFORE DMA issue (no drain attached), masked loads.
// Compute: H-pass-first mfma structure, unchanged from R13 (verified).

typedef _Float16 f16;
typedef __attribute__((ext_vector_type(8))) _Float16 f16x8;
typedef __attribute__((ext_vector_type(4))) float f32x4;

#define IMGW 512
#define IMGH 512
#define NPL 48           // 16*3 planes
#define NBLOCKS (NPL * 8 * 8)   // 3072: 64x64 tile per block
#define NPIX 12582912.0
#define REDT 1024

#define SRW 84                  // dword stride per patch row (21 x 16B)
#define PR 74                   // patch rows
#define IMGOFFD (PR * SRW)      // 6216 dwords per image

// inverse of total f16-weight scale: s = sum of f16(G) = 1048748/2^20, t = s^2
#define INV_T 0.99967202f

// 11-tap gaussian, sigma=1.5, normalized (double-precision precomputed)
__device__ const float G_dev[11] = {0.00102838f, 0.00759876f, 0.03600077f,
                                    0.10936069f, 0.21300554f, 0.26601172f,
                                    0.21300554f, 0.10936069f, 0.03600077f,
                                    0.00759876f, 0.00102838f};

__global__ __launch_bounds__(256, 3) void ssim_main(const float* __restrict__ img1,
                                                    const float* __restrict__ img2,
                                                    float* __restrict__ partial) {
    __shared__ __align__(16) float sP[2 * IMGOFFD];   // 49728 B
    __shared__ float wsum[4];

    const int tid  = threadIdx.x;
    const int lane = tid & 63;
    const int wv   = tid >> 6;         // wave 0..3 (stacked vertically)
    const int l15  = lane & 15;
    const int lg   = lane >> 4;        // 0..3

    const int bid   = blockIdx.x;
    const int plane = bid >> 6;        // 64 tiles per plane
    const int rem   = bid & 63;
    const int by    = rem >> 3;
    const int bx    = rem & 7;
    const int R0    = by * 64 - 5;          // patch row 0 -> image row
    const int AC0   = bx * 64 - 8;          // patch col 0 -> image col (16B aligned)

    const float* __restrict__ p1 = img1 + (size_t)plane * (IMGH * IMGW);
    const float* __restrict__ p2 = img2 + (size_t)plane * (IMGH * IMGW);

    const bool interior = (by >= 1) & (by <= 6) & (bx >= 1) & (bx <= 6);

    // per-lane staging constants: 3 rows per DMA issue, 21 lanes per row
    const int sub_r = lane / 21;            // 0..3 (lane 63 masked off)
    const int cgl   = lane - 21 * sub_r;    // col group 0..20
    const int rbeg  = 16 * wv;                         // own rows begin
    const int rend  = (rbeg + 32 < PR) ? rbeg + 32 : PR;   // own rows end

    if (interior) {
        // ---- barrier-free: each wave stages its own rows, both images ----
        for (int rr = rbeg; rr < rend; rr += 3) {
            const int row = rr + sub_r;
            if (lane < 63 && row < rend) {
                const float* gp = p1 + (size_t)(R0 + row) * IMGW + (AC0 + 4 * cgl);
                __builtin_amdgcn_global_load_lds(gp, &sP[rr * SRW], 16, 0, 0);
            }
        }
        for (int rr = rbeg; rr < rend; rr += 3) {
            const int row = rr + sub_r;
            if (lane < 63 && row < rend) {
                const float* gp = p2 + (size_t)(R0 + row) * IMGW + (AC0 + 4 * cgl);
                __builtin_amdgcn_global_load_lds(gp, &sP[IMGOFFD + rr * SRW], 16, 0, 0);
            }
        }
    } else {
        // ---- edge: zero own rows (both images), barrier, masked DMA ----
        {
            const int nz = (rend - rbeg) * (SRW / 2);    // float2 per image
            float2* z1 = (float2*)&sP[rbeg * SRW];
            float2* z2 = (float2*)&sP[IMGOFFD + rbeg * SRW];
            const float2 zz = make_float2(0.0f, 0.0f);
            for (int i = lane; i < nz; i += 64) { z1[i] = zz; z2[i] = zz; }
        }
        __syncthreads();     // zeros visible before any DMA write lands
        const int rlo = (R0 < 0) ? -R0 : 0;
        const int rhi = (R0 + PR > IMGH) ? (IMGH - R0) : PR;
        const bool cok = ((unsigned)(AC0 + 4 * cgl) < (unsigned)IMGW);
        for (int rr = rbeg; rr < rend; rr += 3) {
            const int row = rr + sub_r;
            if (lane < 63 && row < rend && row >= rlo && row < rhi && cok) {
                const float* gp = p1 + (size_t)(R0 + row) * IMGW + (AC0 + 4 * cgl);
                __builtin_amdgcn_global_load_lds(gp, &sP[rr * SRW], 16, 0, 0);
            }
        }
        for (int rr = rbeg; rr < rend; rr += 3) {
            const int row = rr + sub_r;
            if (lane < 63 && row < rend && row >= rlo && row < rhi && cok) {
                const float* gp = p2 + (size_t)(R0 + row) * IMGW + (AC0 + 4 * cgl);
                __builtin_amdgcn_global_load_lds(gp, &sP[IMGOFFD + rr * SRW], 16, 0, 0);
            }
        }
    }

    // per-wave drain of own DMA queue; fence the scheduler so no LDS read hoists
    asm volatile("s_waitcnt vmcnt(0)" ::: "memory");
    __builtin_amdgcn_sched_barrier(0);

    // ---------- band fragments: B[k][n], k = kap(lg,j), n = l15 ----------
    f16x8 bbH, bbV;
    #pragma unroll
    for (int j = 0; j < 8; ++j) {
        const int kj = (j < 4) ? (4 * lg + j) : (16 + 4 * lg + (j - 4));
        const int tH = kj - l15 - 3;    // H: patch col halo offset 3
        const int tV = kj - l15;        // V: window row 0 = outrow - 5
        bbH[j] = (f16)((tH >= 0 && tH < 11) ? G_dev[tH] : 0.0f);
        bbV[j] = (f16)((tV >= 0 && tV < 11) ? G_dev[tV] : 0.0f);
    }

    const f32x4 zero4 = {0.0f, 0.0f, 0.0f, 0.0f};

    const int rowA = 16 * wv + l15;
    int rowB = 16 * wv + 16 + l15;
    if (rowB > PR - 1) rowB = PR - 1;       // dead k-slots >=26 have bbV=0

    float acc = 0.0f;
    const float C1 = 1.0e-4f;   // 0.01^2
    const float C2 = 9.0e-4f;   // 0.03^2

    #pragma unroll
    for (int m = 0; m < 4; ++m) {
        const int cg = 16 * m + 4 * lg;    // k-slot col group (16B aligned)
        f32x4 D0[5], D1[5];
        #pragma unroll
        for (int s = 0; s < 2; ++s) {
            const int row = s ? rowB : rowA;
            const float* __restrict__ r1 = &sP[row * SRW];
            const float* __restrict__ r2 = &sP[IMGOFFD + row * SRW];
            const f32x4 xa = *(const f32x4*)&r1[cg];
            const f32x4 xb = *(const f32x4*)&r1[cg + 16];
            const f32x4 ya = *(const f32x4*)&r2[cg];
            const f32x4 yb = *(const f32x4*)&r2[cg + 16];
            f16x8 fx, fy;
            #pragma unroll
            for (int e = 0; e < 4; ++e) {
                fx[e]     = (f16)xa[e];
                fx[e + 4] = (f16)xb[e];
                fy[e]     = (f16)ya[e];
                fy[e + 4] = (f16)yb[e];
            }
            const f16x8 fxx = fx * fx;   // v_pk_mul_f16
            const f16x8 fyy = fy * fy;
            const f16x8 fxy = fx * fy;
            f32x4* D = s ? D1 : D0;
            D[0] = __builtin_amdgcn_mfma_f32_16x16x32_f16(fx,  bbH, zero4, 0, 0, 0);
            D[1] = __builtin_amdgcn_mfma_f32_16x16x32_f16(fy,  bbH, zero4, 0, 0, 0);
            D[2] = __builtin_amdgcn_mfma_f32_16x16x32_f16(fxx, bbH, zero4, 0, 0, 0);
            D[3] = __builtin_amdgcn_mfma_f32_16x16x32_f16(fyy, bbH, zero4, 0, 0, 0);
            D[4] = __builtin_amdgcn_mfma_f32_16x16x32_f16(fxy, bbH, zero4, 0, 0, 0);
        }
        // V-pass: lane's H outputs (rows 4lg+reg, col l15) ARE its A-fragment
        f32x4 h[5];
        #pragma unroll
        for (int q = 0; q < 5; ++q) {
            f16x8 av;
            #pragma unroll
            for (int j = 0; j < 4; ++j) {
                av[j]     = (f16)D0[q][j];
                av[j + 4] = (f16)D1[q][j];
            }
            h[q] = __builtin_amdgcn_mfma_f32_16x16x32_f16(av, bbV, zero4, 0, 0, 0);
            h[q] *= INV_T;   // remove f16-weight-sum scale (s^2 per quantity)
        }
        #pragma unroll
        for (int r = 0; r < 4; ++r) {
            const float mu1 = h[0][r], mu2 = h[1][r];
            const float exx = h[2][r], eyy = h[3][r], exy = h[4][r];
            const float mu1s = mu1 * mu1;
            const float mu2s = mu2 * mu2;
            const float mu12 = mu1 * mu2;
            const float s1  = exx - mu1s;
            const float s2  = eyy - mu2s;
            const float s12 = exy - mu12;
            const float num = fmaf(2.0f, mu12, C1) * fmaf(2.0f, s12, C2);
            const float den = (mu1s + mu2s + C1) * (s1 + s2 + C2);
            float rd = __builtin_amdgcn_rcpf(den);   // den > 0 always
            rd = rd * fmaf(-den, rd, 2.0f);          // Newton step
            acc = fmaf(num, rd, acc);
        }
    }

    // ---------- block reduction ----------
    #pragma unroll
    for (int off = 32; off > 0; off >>= 1)
        acc += __shfl_down(acc, off, 64);
    if (lane == 0) wsum[wv] = acc;
    __syncthreads();
    if (tid == 0)
        partial[bid] = (wsum[0] + wsum[1]) + (wsum[2] + wsum[3]);
}

__global__ __launch_bounds__(REDT) void ssim_reduce(const float* __restrict__ partial,
                                                    float* __restrict__ out) {
    const int tid = threadIdx.x;
    double s = 0.0;
    for (int i = tid; i < NBLOCKS; i += REDT)
        s += (double)partial[i];
    #pragma unroll
    for (int off = 32; off > 0; off >>= 1)
        s += __shfl_down(s, off, 64);
    __shared__ double wsd[REDT / 64];
    if ((tid & 63) == 0) wsd[tid >> 6] = s;
    __syncthreads();
    if (tid == 0) {
        double t = 0.0;
        #pragma unroll
        for (int i = 0; i < REDT / 64; ++i) t += wsd[i];
        out[0] = (float)(t / NPIX);
    }
}

extern "C" void kernel_launch(void* const* d_in, const int* in_sizes, int n_in,
                              void* d_out, int out_size, void* d_ws, size_t ws_size,
                              hipStream_t stream) {
    const float* img1 = (const float*)d_in[0];
    const float* img2 = (const float*)d_in[1];
    float* partial = (float*)d_ws;      // 3072 floats
    float* out = (float*)d_out;
    ssim_main<<<NBLOCKS, 256, 0, stream>>>(img1, img2, partial);
    ssim_reduce<<<1, REDT, 0, stream>>>(partial, out);
}